// Round 4
// baseline (3820.771 us; speedup 1.0000x reference)
//
#include <hip/hip_runtime.h>

static constexpr int BB = 16;      // batches
static constexpr int NN = 325;     // nodes
static constexpr int DD = 64;      // channels
static constexpr int SEQ = 12;
static constexpr int MAXDEG = 80;  // Binom(324,0.1): mean 32.4, sd 5.4 -> 8.8 sigma
static constexpr int NPB = 21;     // nodes per block (16 chunks/batch)
static constexpr int SLDS = 68;    // padded slab row stride (dwords), float4-aligned
static constexpr float DT = 0.1f;
static constexpr float NEG = 0.2f;
static constexpr float THRESH = 0.9f;

__device__ __forceinline__ float rdl(float v, int sl) {
  return __int_as_float(__builtin_amdgcn_readlane(__float_as_int(v), sl));
}

// matvec for this wave's 4 nodes (weights in WREG VGPR array, x4 broadcast via
// readlane) + h write + es(LDS)/ed(global) score emit. Macro so the VGPR weight
// array is used with compile-time indices only (no pointer param -> no spill).
#define MATVEC_EMIT(WREG, X4, ASL, ADL, POUT, EDOUT, HOUT)                      \
  do {                                                                          \
    _Pragma("unroll") for (int u2 = 0; u2 < 4; ++u2) {                          \
      int i2l = wv * 4 + u2;                                                    \
      if (i2l < cnt) {                                                          \
        int i2 = n0 + i2l;                                                      \
        float o = 0.f;                                                          \
        _Pragma("unroll") for (int dq = 0; dq < 16; ++dq) {                     \
          int sl = (u2 << 4) + dq;                                              \
          o = fmaf(rdl((X4).x, sl), WREG[4 * dq + 0], o);                       \
          o = fmaf(rdl((X4).y, sl), WREG[4 * dq + 1], o);                       \
          o = fmaf(rdl((X4).z, sl), WREG[4 * dq + 2], o);                       \
          o = fmaf(rdl((X4).w, sl), WREG[4 * dq + 3], o);                       \
        }                                                                       \
        HOUT[((size_t)batch * NN + i2) * DD + lane] = o;                        \
        float p = o * (ASL), qd = o * (ADL);                                    \
        _Pragma("unroll") for (int mm = 1; mm < 16; mm <<= 1) {                 \
          p += __shfl_xor(p, mm, 64);                                           \
          qd += __shfl_xor(qd, mm, 64);                                         \
        }                                                                       \
        if ((lane & 15) == 0) {                                                 \
          les[POUT][i2l][lane >> 4] = p;                                        \
          EDOUT[((size_t)batch * NN + i2) * 4 + (lane >> 4)] = qd;              \
        }                                                                       \
      }                                                                         \
    }                                                                           \
  } while (0)

__global__ __launch_bounds__(512, 2) void ode_persist(
    const float* __restrict__ y0, const float* __restrict__ graph,
    const float* __restrict__ Wg, const float* __restrict__ a_src,
    const float* __restrict__ a_dst, const float* __restrict__ W1,
    const float* __restrict__ b1, const float* __restrict__ W2,
    const float* __restrict__ b2, float* __restrict__ out,
    float* __restrict__ hA, float* __restrict__ hB,
    float* __restrict__ ed0g, float* __restrict__ ed1g, int* __restrict__ bar) {
  __shared__ float slab[NN * SLDS];            // 88.4 KB
  __shared__ float sed[NN * 4];                // 5.2 KB
  __shared__ float wbuf[NPB][MAXDEG * 4];      // 26.9 KB
  __shared__ unsigned short jbuf[NPB][MAXDEG]; // 3.4 KB (persistent adjacency)
  __shared__ int sdeg[NPB];
  __shared__ float les[2][NPB][4];             // own-node es scores

  const int tid = threadIdx.x, lane = tid & 63, wv = tid >> 6;
  const int q = lane & 15, u = lane >> 4, headq = q >> 2;
  const int batch = blockIdx.x & 15, chunk = blockIdx.x >> 4;
  const int n0 = chunk * NPB;
  const int cnt = min(NPB, NN - n0);
  const int il = wv * 4 + u;
  const int i = n0 + il;
  const bool active = il < cnt;
  int* barb = bar + batch * 64;  // 256B-separated per-batch {count, generation}

  // persistent VGPR state: both GAT weight columns + attention vectors + head consts
  float wr0[64], wr1[64];
#pragma unroll
  for (int d = 0; d < 64; ++d) {
    wr0[d] = Wg[d * 64 + lane];
    wr1[d] = Wg[4096 + d * 64 + lane];
  }
  const float as0 = a_src[lane], ad0 = a_dst[lane];
  const float as1 = a_src[64 + lane], ad1 = a_dst[64 + lane];
  const float b1l = b1[lane], w2l = W2[lane], b2s = b2[0];

  // per-batch two-level barrier: one rep thread pays the cache-wide fence
  auto barrier = [&](int target) {
    __syncthreads();  // all waves' global writes drained to L2 (vmcnt 0)
    if (tid == 0) {
      __threadfence();  // release: wb L2 -> LLC (cache-wide, covers whole block)
      int old = __hip_atomic_fetch_add(barb, 1, __ATOMIC_ACQ_REL, __HIP_MEMORY_SCOPE_AGENT);
      if (old == 15) {
        __hip_atomic_store(barb, 0, __ATOMIC_RELAXED, __HIP_MEMORY_SCOPE_AGENT);
        __hip_atomic_fetch_add(barb + 1, 1, __ATOMIC_RELEASE, __HIP_MEMORY_SCOPE_AGENT);
      } else {
        while (__hip_atomic_load(barb + 1, __ATOMIC_ACQUIRE, __HIP_MEMORY_SCOPE_AGENT) < target)
          __builtin_amdgcn_s_sleep(2);
      }
      __threadfence();  // acquire: inv L1 (this CU, shared by block) + L2
    }
    __syncthreads();
  };

  // ---- adjacency for own nodes, built once into LDS (ballot compaction)
  for (int rr = wv; rr < cnt; rr += 8) {
    int r = n0 + rr, dc = 0;
    for (int bj = 0; bj < NN; bj += 64) {
      int j = bj + lane;
      bool pred = (j < NN) && ((graph[(size_t)r * NN + j] > THRESH) || (j == r));
      unsigned long long mk = __ballot(pred);
      int pos = dc + (int)__popcll(mk & ((1ULL << lane) - 1ULL));
      if (pred && pos < MAXDEG) jbuf[rr][pos] = (unsigned short)j;
      dc += (int)__popcll(mk);
    }
    if (lane == 0) sdeg[rr] = min(dc, MAXDEG);
  }
  __syncthreads();
  const int dg = active ? sdeg[il] : 0;
  int dgw = dg;
  dgw = max(dgw, __shfl_xor(dgw, 16, 64));
  dgw = max(dgw, __shfl_xor(dgw, 32, 64));
  const int ilc = active ? il : 0;

  // stage slab+ed, then sparse-softmax aggregate own 4 nodes (R3-verified math)
  auto stage_and_agg = [&](const float* hin, const float* edin, int ples, float& ax,
                           float& ay, float& az, float& aw, float& den) {
    for (int grp = wv; grp < 82; grp += 8) {
      int r = grp * 4 + u;
      if (r < NN)
        *(float4*)&slab[r * SLDS + q * 4] =
            *(const float4*)(hin + ((size_t)batch * NN + r) * DD + q * 4);
    }
    for (int idx = tid; idx < NN * 4; idx += 512)
      sed[idx] = edin[(size_t)batch * NN * 4 + idx];
    __syncthreads();
    if (active) {
      float esi = les[ples][il][q & 3];
      for (int it = 0; it * 4 < dg; ++it) {
        int nbr = it * 4 + (q >> 2);
        if (nbr < dg) {
          int j = jbuf[il][nbr];
          float e = esi + sed[j * 4 + (q & 3)];
          e = fmaxf(e, NEG * e);              // leaky_relu
          wbuf[il][it * 16 + q] = __expf(e);  // |e| is O(10): exp safe in fp32
        }
      }
    }
    __builtin_amdgcn_wave_barrier();
    ax = ay = az = aw = den = 0.f;
    for (int jj = 0; jj < dgw; ++jj) {
      int jc = jj < dg ? jj : 0;
      int j = jbuf[ilc][jc];
      float w = wbuf[ilc][jc * 4 + headq];
      if (!(active && jj < dg)) w = 0.f;
      const float4 h = *(const float4*)&slab[j * SLDS + q * 4];
      den += w;
      ax = fmaf(w, h.x, ax);
      ay = fmaf(w, h.y, ay);
      az = fmaf(w, h.z, az);
      aw = fmaf(w, h.w, aw);
    }
  };

  // head MLP (W1 streamed from global: used 13x only), writes out[batch][tt][node]
  auto head_emit = [&](float4 x4, int tt) {
#pragma unroll
    for (int u2 = 0; u2 < 4; ++u2) {
      int i2l = wv * 4 + u2;
      if (i2l < cnt) {
        float oh = 0.f;
#pragma unroll
        for (int dq = 0; dq < 16; ++dq) {
          int sl = (u2 << 4) + dq;
          oh = fmaf(rdl(x4.x, sl), W1[(4 * dq + 0) * 64 + lane], oh);
          oh = fmaf(rdl(x4.y, sl), W1[(4 * dq + 1) * 64 + lane], oh);
          oh = fmaf(rdl(x4.z, sl), W1[(4 * dq + 2) * 64 + lane], oh);
          oh = fmaf(rdl(x4.w, sl), W1[(4 * dq + 3) * 64 + lane], oh);
        }
        float z = tanhf(oh + b1l) * w2l;
#pragma unroll
        for (int mm = 1; mm < 64; mm <<= 1) z += __shfl_xor(z, mm, 64);
        if (lane == 0) out[((size_t)batch * (SEQ + 1) + tt) * NN + (n0 + i2l)] = z + b2s;
      }
    }
  };

  // ---- init: yy=y0 (regs), hA = y0@W0 + layer-0 scores, head output t=0
  float4 yyr = {0.f, 0.f, 0.f, 0.f}, accr = {0.f, 0.f, 0.f, 0.f};
  if (active) yyr = *(const float4*)(y0 + ((size_t)batch * NN + i) * DD + q * 4);
  {
    float4 x4 = yyr;
    MATVEC_EMIT(wr0, x4, as0, ad0, 0, ed0g, hA);
    head_emit(x4, 0);
  }
  int tgt = 0;
  barrier(++tgt);

  // ---- 12 RK4 steps x 4 stages; 2 barriers per stage (one per GAT layer)
  for (int t = 0; t < SEQ; ++t) {
    for (int s = 0; s < 4; ++s) {
      // phase A: layer-0 agg (hA, ed0, les0) -> elu -> @W1 -> hB, ed1, les1
      float ax, ay, az, aw, den;
      stage_and_agg(hA, ed0g, 0, ax, ay, az, aw, den);
      float4 x4 = {0.f, 0.f, 0.f, 0.f};
      if (active) {
        float inv = 1.f / den;
        ax *= inv; ay *= inv; az *= inv; aw *= inv;
        x4.x = ax > 0.f ? ax : __expf(ax) - 1.f;
        x4.y = ay > 0.f ? ay : __expf(ay) - 1.f;
        x4.z = az > 0.f ? az : __expf(az) - 1.f;
        x4.w = aw > 0.f ? aw : __expf(aw) - 1.f;
      }
      MATVEC_EMIT(wr1, x4, as1, ad1, 1, ed1g, hB);
      barrier(++tgt);

      // phase B: layer-1 agg (hB, ed1, les1) -> RK stage s (regs) -> @W0 -> hA, ed0, les0
      stage_and_agg(hB, ed1g, 1, ax, ay, az, aw, den);
      x4.x = x4.y = x4.z = x4.w = 0.f;
      if (active) {
        float inv = 1.f / den;
        ax *= inv; ay *= inv; az *= inv; aw *= inv;
        if (s == 0) {
          accr.x = ax; accr.y = ay; accr.z = az; accr.w = aw;
          x4.x = yyr.x + 0.5f * DT * ax; x4.y = yyr.y + 0.5f * DT * ay;
          x4.z = yyr.z + 0.5f * DT * az; x4.w = yyr.w + 0.5f * DT * aw;
        } else if (s == 1 || s == 2) {
          accr.x += 2.f * ax; accr.y += 2.f * ay;
          accr.z += 2.f * az; accr.w += 2.f * aw;
          const float c = (s == 1) ? 0.5f * DT : DT;
          x4.x = yyr.x + c * ax; x4.y = yyr.y + c * ay;
          x4.z = yyr.z + c * az; x4.w = yyr.w + c * aw;
        } else {
          x4.x = yyr.x + (DT / 6.f) * (accr.x + ax);
          x4.y = yyr.y + (DT / 6.f) * (accr.y + ay);
          x4.z = yyr.z + (DT / 6.f) * (accr.z + az);
          x4.w = yyr.w + (DT / 6.f) * (accr.w + aw);
          yyr = x4;  // y_{t+1}
        }
      }
      MATVEC_EMIT(wr0, x4, as0, ad0, 0, ed0g, hA);
      if (s == 3) head_emit(x4, t + 1);
      barrier(++tgt);
    }
  }
}

extern "C" void kernel_launch(void* const* d_in, const int* in_sizes, int n_in,
                              void* d_out, int out_size, void* d_ws, size_t ws_size,
                              hipStream_t stream) {
  const float* y0 = (const float*)d_in[0];
  const float* graph = (const float*)d_in[1];
  const float* Wg = (const float*)d_in[2];
  const float* a_src = (const float*)d_in[3];
  const float* a_dst = (const float*)d_in[4];
  const float* W1 = (const float*)d_in[5];
  const float* b1 = (const float*)d_in[6];
  const float* W2 = (const float*)d_in[7];
  const float* b2 = (const float*)d_in[8];
  float* out = (float*)d_out;

  char* ws = (char*)d_ws;
  size_t off = 0;
  auto take = [&](size_t bytes) -> char* {
    char* p = ws + off;
    off += (bytes + 255) & ~size_t(255);
    return p;
  };
  float* hA = (float*)take((size_t)BB * NN * DD * sizeof(float));
  float* hB = (float*)take((size_t)BB * NN * DD * sizeof(float));
  float* ed0g = (float*)take((size_t)BB * NN * 4 * sizeof(float));
  float* ed1g = (float*)take((size_t)BB * NN * 4 * sizeof(float));
  int* bar = (int*)take(16 * 64 * sizeof(int));
  if (off > ws_size) return;  // loud failure: output stays poisoned

  hipMemsetAsync(bar, 0, 16 * 64 * sizeof(int), stream);  // barrier counters = 0

  void* args[] = {&y0, &graph, &Wg, &a_src, &a_dst, &W1, &b1,
                  &W2, &b2, &out, &hA, &hB, &ed0g, &ed1g, &bar};
  hipLaunchCooperativeKernel((void*)ode_persist, dim3(256), dim3(512), args, 0, stream);
}

// Round 5
// 1653.279 us; speedup vs baseline: 2.3110x; 2.3110x over previous
//
#include <hip/hip_runtime.h>

static constexpr int BB = 16;      // batches
static constexpr int NN = 325;     // nodes
static constexpr int DD = 64;      // channels
static constexpr int SEQ = 12;
static constexpr int MAXDEG = 80;  // Binom(324,0.1): mean 32.4, sd 5.4 -> 8.8 sigma
static constexpr int NPB = 21;     // nodes per block (16 chunks/batch)
static constexpr float DT = 0.1f;
static constexpr float NEG = 0.2f;
static constexpr float THRESH = 0.9f;

typedef __attribute__((address_space(1))) const void gvoid_t;
typedef __attribute__((address_space(3))) void lvoid_t;

__device__ __forceinline__ float rdl(float v, int sl) {
  return __int_as_float(__builtin_amdgcn_readlane(__float_as_int(v), sl));
}

// async 16B/lane global->LDS, aux=1 (SC0: bypass L1 so same-XCD L2 writes are fresh)
__device__ __forceinline__ void async16(const float* g, float* l) {
  __builtin_amdgcn_global_load_lds((gvoid_t*)g, (lvoid_t*)l, 16, 0, 1);
}

// matvec for this wave's 4 nodes (weights in VGPR array WREG, x4 broadcast via
// readlane) + h write + es(LDS)/ed(global) score emit. Macro keeps WREG indices
// compile-time (no pointer param -> stays in registers).
#define MATVEC_EMIT(WREG, X4, ASL, ADL, POUT, EDOUT, HOUT)                      \
  do {                                                                          \
    _Pragma("unroll") for (int u2 = 0; u2 < 4; ++u2) {                          \
      int i2l = wv * 4 + u2;                                                    \
      if (i2l < cnt) {                                                          \
        int i2 = n0 + i2l;                                                      \
        float o = 0.f;                                                          \
        _Pragma("unroll") for (int dq = 0; dq < 16; ++dq) {                     \
          int sl = (u2 << 4) + dq;                                              \
          o = fmaf(rdl((X4).x, sl), WREG[4 * dq + 0], o);                       \
          o = fmaf(rdl((X4).y, sl), WREG[4 * dq + 1], o);                       \
          o = fmaf(rdl((X4).z, sl), WREG[4 * dq + 2], o);                       \
          o = fmaf(rdl((X4).w, sl), WREG[4 * dq + 3], o);                       \
        }                                                                       \
        HOUT[((size_t)batch * NN + i2) * DD + lane] = o;                        \
        float p = o * (ASL), qd = o * (ADL);                                    \
        _Pragma("unroll") for (int mm = 1; mm < 16; mm <<= 1) {                 \
          p += __shfl_xor(p, mm, 64);                                           \
          qd += __shfl_xor(qd, mm, 64);                                         \
        }                                                                       \
        if ((lane & 15) == 0) {                                                 \
          les[POUT][i2l][lane >> 4] = p;                                        \
          EDOUT[((size_t)batch * NN + i2) * 4 + (lane >> 4)] = qd;              \
        }                                                                       \
      }                                                                         \
    }                                                                           \
  } while (0)

__global__ __launch_bounds__(512) void ode_persist(
    const float* __restrict__ y0, const float* __restrict__ graph,
    const float* __restrict__ Wg, const float* __restrict__ a_src,
    const float* __restrict__ a_dst, const float* __restrict__ W1,
    const float* __restrict__ b1, const float* __restrict__ W2,
    const float* __restrict__ b2, float* __restrict__ out,
    float* __restrict__ hA, float* __restrict__ hB,
    float* __restrict__ ed0g, float* __restrict__ ed1g, int* __restrict__ bar) {
  __shared__ float slab[328 * 64];              // 82 KB, stride-64: row reads hit all banks evenly
  __shared__ float sed[1536];                   // 6 KB (1300 used; sized for DMA overrun)
  __shared__ float wbuf[NPB][MAXDEG * 4];       // 26.9 KB
  __shared__ unsigned short jbuf[NPB][MAXDEG];  // 3.4 KB persistent adjacency
  __shared__ int sdeg[NPB];
  __shared__ float les[2][NPB][4];              // own-node es scores
  __shared__ int smode;

  const int tid = threadIdx.x, lane = tid & 63, wv = tid >> 6;
  const int q = lane & 15, u = lane >> 4, headq = q >> 2;
  const int batch = blockIdx.x & 15, chunk = blockIdx.x >> 4;
  const int n0 = chunk * NPB;
  const int cnt = min(NPB, NN - n0);
  const int il = wv * 4 + u;
  const int i = n0 + il;
  const bool active = il < cnt;
  int* barb = bar + batch * 64;      // per-batch {count, gen}, 256B-separated
  int* gbar = bar + 16 * 64;         // one-time grid barrier
  int* xcctab = bar + 17 * 64;       // 256 XCC entries

  // ---- XCD-uniformity self-check (correctness insurance for the fast barrier)
  if (tid == 0) {
    int xcc = __builtin_amdgcn_s_getreg((3 << 11) | 20) & 0xf;  // HW_REG_XCC_ID[3:0]
    __hip_atomic_store(&xcctab[blockIdx.x], xcc + 1, __ATOMIC_RELAXED,
                       __HIP_MEMORY_SCOPE_SYSTEM);
    __threadfence_system();
    __hip_atomic_fetch_add(gbar, 1, __ATOMIC_RELAXED, __HIP_MEMORY_SCOPE_SYSTEM);
    while (__hip_atomic_load(gbar, __ATOMIC_RELAXED, __HIP_MEMORY_SCOPE_SYSTEM) < 256)
      __builtin_amdgcn_s_sleep(1);
    __threadfence_system();
  }
  __syncthreads();
  if (wv == 0) {
    int v = 1;
    if (lane < 16)
      v = __hip_atomic_load(&xcctab[batch + 16 * lane], __ATOMIC_RELAXED,
                            __HIP_MEMORY_SCOPE_SYSTEM);
    int v0 = __shfl(v, 0, 64);
    bool ok = (lane < 16) ? (v == v0) : true;
    unsigned long long m = __ballot(ok);
    if (lane == 0) smode = (m == ~0ULL) ? 1 : 0;
  }
  __syncthreads();
  const int fastmode = smode;  // all 16 blocks of a batch on one XCD -> L2-coherent

  // per-batch barrier. Fast: vmcnt drain + relaxed LLC atomics + per-CU L1 inv.
  // Slow (fallback if mapping assumption failed): full fences around the atomics.
  auto barrier = [&](int target) {
    __syncthreads();  // drains each wave's stores to L2 (vmcnt 0) before arrive
    if (tid == 0) {
      if (!fastmode) __threadfence();
      int old = __hip_atomic_fetch_add(&barb[0], 1, __ATOMIC_RELAXED,
                                       __HIP_MEMORY_SCOPE_AGENT);
      if (old == 16 * target - 1) {  // monotonic count: no reset race
        __hip_atomic_store(&barb[1], target, __ATOMIC_RELAXED, __HIP_MEMORY_SCOPE_AGENT);
      } else {
        while (__hip_atomic_load(&barb[1], __ATOMIC_RELAXED, __HIP_MEMORY_SCOPE_AGENT) <
               target)
          __builtin_amdgcn_s_sleep(1);
      }
      if (!fastmode)
        __threadfence();
      else
        asm volatile("buffer_inv\ns_waitcnt vmcnt(0)" ::: "memory");  // L1 only
    }
    __syncthreads();
  };

  // persistent VGPR state (launch_bounds(512) -> 256-VGPR budget: no spills)
  float wr0[64], wr1[64];
#pragma unroll
  for (int d = 0; d < 64; ++d) {
    wr0[d] = Wg[d * 64 + lane];
    wr1[d] = Wg[4096 + d * 64 + lane];
  }
  const float as0 = a_src[lane], ad0 = a_dst[lane];
  const float as1 = a_src[64 + lane], ad1 = a_dst[64 + lane];
  const float b1l = b1[lane], w2l = W2[lane], b2s = b2[0];

  // ---- adjacency for own nodes, built once into LDS (ballot compaction)
  for (int rr = wv; rr < cnt; rr += 8) {
    int r = n0 + rr, dc = 0;
    for (int bj = 0; bj < NN; bj += 64) {
      int j = bj + lane;
      bool pred = (j < NN) && ((graph[(size_t)r * NN + j] > THRESH) || (j == r));
      unsigned long long mk = __ballot(pred);
      int pos = dc + (int)__popcll(mk & ((1ULL << lane) - 1ULL));
      if (pred && pos < MAXDEG) jbuf[rr][pos] = (unsigned short)j;
      dc += (int)__popcll(mk);
    }
    if (lane == 0) sdeg[rr] = min(dc, MAXDEG);
  }
  __syncthreads();
  const int dg = active ? sdeg[il] : 0;
  int dgw = dg;
  dgw = max(dgw, __shfl_xor(dgw, 16, 64));
  dgw = max(dgw, __shfl_xor(dgw, 32, 64));
  const int ilc = active ? il : 0;

  // stage slab+ed via async LDS-DMA (sc0), then sparse-softmax aggregate own 4 nodes
  auto stage_and_agg = [&](const float* hin, const float* edin, int ples, float& ax,
                           float& ay, float& az, float& aw, float& den) {
    const float* hb = hin + (size_t)batch * NN * DD;
    for (int grp = wv; grp < 82; grp += 8)  // 82*4=328 rows (3-row overrun: mapped, unused)
      async16(hb + grp * 256 + lane * 4, &slab[grp * 256 + lane * 4]);
    const float* eb = edin + (size_t)batch * NN * 4;
    for (int grp = wv; grp < 6; grp += 8)
      async16(eb + grp * 256 + lane * 4, &sed[grp * 256 + lane * 4]);
    __syncthreads();  // vmcnt drain covers the LDS-DMA
    if (active) {
      float esi = les[ples][il][q & 3];
      for (int it = 0; it * 4 < dg; ++it) {
        int nbr = it * 4 + (q >> 2);
        if (nbr < dg) {
          int j = jbuf[il][nbr];
          float e = esi + sed[j * 4 + (q & 3)];
          e = fmaxf(e, NEG * e);              // leaky_relu
          wbuf[il][it * 16 + q] = __expf(e);  // |e| is O(10): exp safe in fp32
        }
      }
    }
    __builtin_amdgcn_wave_barrier();
    ax = ay = az = aw = den = 0.f;
    for (int jj = 0; jj < dgw; ++jj) {
      int jc = jj < dg ? jj : 0;
      int j = jbuf[ilc][jc];
      float w = wbuf[ilc][jc * 4 + headq];
      if (!(active && jj < dg)) w = 0.f;
      const float4 h = *(const float4*)&slab[j * 64 + q * 4];
      den += w;
      ax = fmaf(w, h.x, ax);
      ay = fmaf(w, h.y, ay);
      az = fmaf(w, h.z, az);
      aw = fmaf(w, h.w, aw);
    }
  };

  // head MLP (W1 streamed from global: used 13x only)
  auto head_emit = [&](float4 x4, int tt) {
#pragma unroll
    for (int u2 = 0; u2 < 4; ++u2) {
      int i2l = wv * 4 + u2;
      if (i2l < cnt) {
        float oh = 0.f;
#pragma unroll
        for (int dq = 0; dq < 16; ++dq) {
          int sl = (u2 << 4) + dq;
          oh = fmaf(rdl(x4.x, sl), W1[(4 * dq + 0) * 64 + lane], oh);
          oh = fmaf(rdl(x4.y, sl), W1[(4 * dq + 1) * 64 + lane], oh);
          oh = fmaf(rdl(x4.z, sl), W1[(4 * dq + 2) * 64 + lane], oh);
          oh = fmaf(rdl(x4.w, sl), W1[(4 * dq + 3) * 64 + lane], oh);
        }
        float z = tanhf(oh + b1l) * w2l;
#pragma unroll
        for (int mm = 1; mm < 64; mm <<= 1) z += __shfl_xor(z, mm, 64);
        if (lane == 0) out[((size_t)batch * (SEQ + 1) + tt) * NN + (n0 + i2l)] = z + b2s;
      }
    }
  };

  // ---- init: y in regs, hA = y0@W0 + layer-0 scores, head output t=0
  float4 yyr = {0.f, 0.f, 0.f, 0.f}, accr = {0.f, 0.f, 0.f, 0.f};
  if (active) yyr = *(const float4*)(y0 + ((size_t)batch * NN + i) * DD + q * 4);
  {
    float4 x4 = yyr;
    MATVEC_EMIT(wr0, x4, as0, ad0, 0, ed0g, hA);
    head_emit(x4, 0);
  }
  int tgt = 0;
  barrier(++tgt);

  // ---- 12 RK4 steps x 4 stages; 2 barriers per stage (one per GAT layer)
  for (int t = 0; t < SEQ; ++t) {
    for (int s = 0; s < 4; ++s) {
      // phase A: layer-0 agg (hA, ed0, les0) -> elu -> @W1 -> hB, ed1, les1
      float ax, ay, az, aw, den;
      stage_and_agg(hA, ed0g, 0, ax, ay, az, aw, den);
      float4 x4 = {0.f, 0.f, 0.f, 0.f};
      if (active) {
        float inv = 1.f / den;
        ax *= inv; ay *= inv; az *= inv; aw *= inv;
        x4.x = ax > 0.f ? ax : __expf(ax) - 1.f;
        x4.y = ay > 0.f ? ay : __expf(ay) - 1.f;
        x4.z = az > 0.f ? az : __expf(az) - 1.f;
        x4.w = aw > 0.f ? aw : __expf(aw) - 1.f;
      }
      MATVEC_EMIT(wr1, x4, as1, ad1, 1, ed1g, hB);
      barrier(++tgt);

      // phase B: layer-1 agg -> RK stage s (regs) -> @W0 -> hA, ed0, les0
      stage_and_agg(hB, ed1g, 1, ax, ay, az, aw, den);
      x4.x = x4.y = x4.z = x4.w = 0.f;
      if (active) {
        float inv = 1.f / den;
        ax *= inv; ay *= inv; az *= inv; aw *= inv;
        if (s == 0) {
          accr.x = ax; accr.y = ay; accr.z = az; accr.w = aw;
          x4.x = yyr.x + 0.5f * DT * ax; x4.y = yyr.y + 0.5f * DT * ay;
          x4.z = yyr.z + 0.5f * DT * az; x4.w = yyr.w + 0.5f * DT * aw;
        } else if (s == 1 || s == 2) {
          accr.x += 2.f * ax; accr.y += 2.f * ay;
          accr.z += 2.f * az; accr.w += 2.f * aw;
          const float c = (s == 1) ? 0.5f * DT : DT;
          x4.x = yyr.x + c * ax; x4.y = yyr.y + c * ay;
          x4.z = yyr.z + c * az; x4.w = yyr.w + c * aw;
        } else {
          x4.x = yyr.x + (DT / 6.f) * (accr.x + ax);
          x4.y = yyr.y + (DT / 6.f) * (accr.y + ay);
          x4.z = yyr.z + (DT / 6.f) * (accr.z + az);
          x4.w = yyr.w + (DT / 6.f) * (accr.w + aw);
          yyr = x4;  // y_{t+1}
        }
      }
      MATVEC_EMIT(wr0, x4, as0, ad0, 0, ed0g, hA);
      if (s == 3) head_emit(x4, t + 1);
      barrier(++tgt);
    }
  }
}

extern "C" void kernel_launch(void* const* d_in, const int* in_sizes, int n_in,
                              void* d_out, int out_size, void* d_ws, size_t ws_size,
                              hipStream_t stream) {
  const float* y0 = (const float*)d_in[0];
  const float* graph = (const float*)d_in[1];
  const float* Wg = (const float*)d_in[2];
  const float* a_src = (const float*)d_in[3];
  const float* a_dst = (const float*)d_in[4];
  const float* W1 = (const float*)d_in[5];
  const float* b1 = (const float*)d_in[6];
  const float* W2 = (const float*)d_in[7];
  const float* b2 = (const float*)d_in[8];
  float* out = (float*)d_out;

  char* ws = (char*)d_ws;
  size_t off = 0;
  auto take = [&](size_t bytes) -> char* {
    char* p = ws + off;
    off += (bytes + 255) & ~size_t(255);
    return p;
  };
  float* hA = (float*)take((size_t)BB * NN * DD * sizeof(float));
  float* hB = (float*)take((size_t)BB * NN * DD * sizeof(float));
  float* ed0g = (float*)take((size_t)BB * NN * 4 * sizeof(float));
  float* ed1g = (float*)take((size_t)BB * NN * 4 * sizeof(float));
  int* bar = (int*)take(2048 * sizeof(int));
  if (off > ws_size) return;  // loud failure: output stays poisoned

  hipMemsetAsync(bar, 0, 2048 * sizeof(int), stream);

  void* args[] = {&y0, &graph, &Wg, &a_src, &a_dst, &W1, &b1,
                  &W2, &b2, &out, &hA, &hB, &ed0g, &ed1g, &bar};
  hipLaunchCooperativeKernel((void*)ode_persist, dim3(256), dim3(512), args, 0, stream);
}